// Round 6
// baseline (7342.646 us; speedup 1.0000x reference)
//
#include <hip/hip_runtime.h>
#include <math.h>

// ---------------------------------------------------------------------------
// MoE layer — naive VALU baseline, round 6: OUTPUT WRITTEN AS FLOAT32.
// Theory: harness reads d_out as f32 (reference output dtype); bf16 writes
// in R3-R5 produced the observed decorrelated absmax 3.3828 via pair-packing.
// Inputs f32 (device-proven R3). Internal: f32 except hidden/aw (bf16, space).
// B=4, S=2048, D=1024, H=2048, A=128, E=8, N=8192.
// ---------------------------------------------------------------------------

typedef __bf16 bf16_t;

__device__ __forceinline__ float b2f(bf16_t v) { return (float)v; }
__device__ __forceinline__ bf16_t f2b(float v) { return (bf16_t)v; }
__device__ __forceinline__ float siluf(float v) { return v / (1.f + expf(-v)); }

static constexpr int Bb = 4, S = 2048, D = 1024, H = 2048, A = 128, E = 8;
static constexpr int N = Bb * S;

template <int DT>
__device__ __forceinline__ float ldT(const void* p, long i) {
  if constexpr (DT == 0) return reinterpret_cast<const float*>(p)[i];
  else return b2f(reinterpret_cast<const bf16_t*>(p)[i]);
}

// ---------------------------------------------------------------------------
// Naive tiled GEMM, one output/thread, 16x16 tiles.
// TRB=0 (NT): C[m,n] = sum_k A[m,k]*B[n,k]   (B is [Nn,K] row-major)
// TRB=1 (NN): C[m,n] = sum_k A[m,k]*B[k,n]   (B is [K,Nn] row-major)
// MODE: 0 f32 store; 1 bf16 store; 2 silu(clip(v,-5,5)) bf16;
//       3 bf16 RMW C += 0.1*v; 4 bf16 RMW C = C*aux[row]+0.1*v;
//       5 f32 RMW C = C*aux[row] + 0.1*v
// ---------------------------------------------------------------------------
template <int ADT, int BDT, int TRB, int MODE>
__global__ __launch_bounds__(256) void gemm16(
    const void* __restrict__ A, const void* __restrict__ B,
    void* __restrict__ Cv, int M, int Nn, int K, const float* __restrict__ aux) {
  __shared__ float As[16][17];
  __shared__ float Bs[16][17];
  const int tx = threadIdx.x & 15, ty = threadIdx.x >> 4;
  const int row = blockIdx.y * 16 + ty;
  const int col0 = blockIdx.x * 16;
  const int col = col0 + tx;
  float acc = 0.f;
  for (int k0 = 0; k0 < K; k0 += 16) {
    As[ty][tx] = ldT<ADT>(A, (long)row * K + k0 + tx);
    if constexpr (TRB == 0)
      Bs[ty][tx] = ldT<BDT>(B, (long)(col0 + ty) * K + k0 + tx);
    else
      Bs[ty][tx] = ldT<BDT>(B, (long)(k0 + ty) * Nn + col0 + tx);
    __syncthreads();
#pragma unroll
    for (int k = 0; k < 16; k++)
      acc += As[ty][k] * (TRB ? Bs[k][tx] : Bs[tx][k]);
    __syncthreads();
  }
  const long o = (long)row * Nn + col;
  if constexpr (MODE == 0) {
    reinterpret_cast<float*>(Cv)[o] = acc;
  } else if constexpr (MODE == 1) {
    reinterpret_cast<bf16_t*>(Cv)[o] = f2b(acc);
  } else if constexpr (MODE == 2) {
    float v = fminf(fmaxf(acc, -5.f), 5.f);
    reinterpret_cast<bf16_t*>(Cv)[o] = f2b(siluf(v));
  } else if constexpr (MODE == 3) {
    bf16_t* C = reinterpret_cast<bf16_t*>(Cv);
    C[o] = f2b(b2f(C[o]) + 0.1f * acc);
  } else if constexpr (MODE == 4) {
    bf16_t* C = reinterpret_cast<bf16_t*>(Cv);
    C[o] = f2b(b2f(C[o]) * aux[row] + 0.1f * acc);
  } else {
    float* C = reinterpret_cast<float*>(Cv);
    C[o] = C[o] * aux[row] + 0.1f * acc;
  }
}

// ---------------------------------------------------------------------------
// Fused gate/up naive GEMM: hidden = silu(x@Wg^T) * (x@Wu^T), bf16 out.
// ---------------------------------------------------------------------------
__global__ __launch_bounds__(256) void gateup16(
    const float* __restrict__ x, const float* __restrict__ Wg,
    const float* __restrict__ Wu, bf16_t* __restrict__ Cg, int M, int Nn, int K) {
  __shared__ float As[16][17];
  __shared__ float B1[16][17];
  __shared__ float B2[16][17];
  const int tx = threadIdx.x & 15, ty = threadIdx.x >> 4;
  const int row = blockIdx.y * 16 + ty;
  const int col0 = blockIdx.x * 16;
  const int col = col0 + tx;
  float ag = 0.f, au = 0.f;
  for (int k0 = 0; k0 < K; k0 += 16) {
    As[ty][tx] = x[(long)row * K + k0 + tx];
    B1[ty][tx] = Wg[(long)(col0 + ty) * K + k0 + tx];
    B2[ty][tx] = Wu[(long)(col0 + ty) * K + k0 + tx];
    __syncthreads();
#pragma unroll
    for (int k = 0; k < 16; k++) {
      ag += As[ty][k] * B1[tx][k];
      au += As[ty][k] * B2[tx][k];
    }
    __syncthreads();
  }
  Cg[(long)row * Nn + col] = f2b(siluf(ag) * au);
}

// ---------------------------------------------------------------------------
// Router: one wave/token, f32 loads, pure f32 math.
// ---------------------------------------------------------------------------
__global__ __launch_bounds__(256) void router_kernel(
    const float* __restrict__ x, const float* __restrict__ Wgr,
    const float* __restrict__ Wer, int* __restrict__ eidx,
    float* __restrict__ fw, float* __restrict__ wsum, float* __restrict__ loss) {
  const int token = blockIdx.x * 4 + (threadIdx.x >> 6);
  const int lane = threadIdx.x & 63;
  const float* xp = x + (long)token * D;
  float xr[16];
#pragma unroll
  for (int i = 0; i < 16; i++) xr[i] = xp[lane + i * 64];
  float dots[6];
#pragma unroll
  for (int w = 0; w < 6; w++) {
    const float* wp = (w < 2) ? (Wgr + (long)w * D) : (Wer + (long)(w - 2) * D);
    float s = 0.f;
#pragma unroll
    for (int i = 0; i < 16; i++) s += xr[i] * wp[lane + i * 64];
#pragma unroll
    for (int off = 32; off; off >>= 1) s += __shfl_xor(s, off);
    dots[w] = s;
  }
  if (lane == 0) {
    float gl0 = dots[0], gl1 = dots[1];
    float mg = fmaxf(gl0, gl1);
    float e0 = expf(gl0 - mg), e1 = expf(gl1 - mg);
    float inv = 1.f / (e0 + e1);
    float gp0 = e0 * inv, gp1 = e1 * inv;
    int gi = (gp1 > gp0) ? 1 : 0;
    float gw = gi ? gp1 : gp0;
    float el[4] = {dots[2], dots[3], dots[4], dots[5]};
    float me = fmaxf(fmaxf(el[0], el[1]), fmaxf(el[2], el[3]));
    float ep[4], es = 0.f;
#pragma unroll
    for (int j = 0; j < 4; j++) { ep[j] = expf(el[j] - me); es += ep[j]; }
    float inve = 1.f / es;
#pragma unroll
    for (int j = 0; j < 4; j++) ep[j] *= inve;
    int i1 = 0;
    for (int j = 1; j < 4; j++) if (ep[j] > ep[i1]) i1 = j;
    int i2 = (i1 == 0) ? 1 : 0;
    for (int j = 0; j < 4; j++) if (j != i1 && j != i2 && ep[j] > ep[i2]) i2 = j;
    float l1 = ep[i1], l2 = ep[i2];
    float ils = 1.f / (l1 + l2 + 1e-7f);
    float f1 = gw * l1 * ils, f2 = gw * l2 * ils;
    eidx[token * 2] = gi * 4 + i1;
    eidx[token * 2 + 1] = gi * 4 + i2;
    fw[token * 2] = f1;
    fw[token * 2 + 1] = f2;
    wsum[token] = f1 + f2;
    atomicAdd(&loss[gi * 4 + i1], f1);
    atomicAdd(&loss[gi * 4 + i2], f2);
    atomicAdd(&loss[8], gl0 * gl0 + gl1 * gl1);
    atomicAdd(&loss[9], el[0] * el[0] + el[1] * el[1] + el[2] * el[2] + el[3] * el[3]);
  }
}

// ---------------------------------------------------------------------------
// Row LayerNorm over A=128, f32 in/out, 1 wave/row.
// ---------------------------------------------------------------------------
__global__ __launch_bounds__(256) void ln_rows_f32(
    const float* __restrict__ in, const float* __restrict__ g,
    const float* __restrict__ b, float* __restrict__ out) {
  const int row = blockIdx.x * 4 + (threadIdx.x >> 6);
  const int lane = threadIdx.x & 63;
  const float* p = in + (long)row * A;
  float x0 = p[lane], x1 = p[lane + 64];
  float s = x0 + x1;
#pragma unroll
  for (int off = 32; off; off >>= 1) s += __shfl_xor(s, off);
  float mean = s * (1.f / 128.f);
  float d0 = x0 - mean, d1 = x1 - mean;
  float q = d0 * d0 + d1 * d1;
#pragma unroll
  for (int off = 32; off; off >>= 1) q += __shfl_xor(q, off);
  float r = rsqrtf(q * (1.f / 128.f) + 1e-5f);
  float* po = out + (long)row * A;
  po[lane] = d0 * r * g[lane] + b[lane];
  po[lane + 64] = d1 * r * g[lane + 64] + b[lane + 64];
}

// ---------------------------------------------------------------------------
// Expert branch, pure f32: hw[n] = sum_k fw_k * LN_e(Wea[e_k] @ h0[n]).
// ---------------------------------------------------------------------------
__global__ __launch_bounds__(128) void expert_adapt_f32(
    const float* __restrict__ h0, const float* __restrict__ Wea,
    const float* __restrict__ ln_eg, const float* __restrict__ ln_eb,
    const int* __restrict__ eidx, const float* __restrict__ fw,
    float* __restrict__ hw) {
  const int n = blockIdx.x;
  const int c = threadIdx.x;
  __shared__ float h0s[128];
  __shared__ float red[4];
  h0s[c] = h0[(long)n * A + c];
  __syncthreads();
  float out = 0.f;
  for (int k = 0; k < 2; k++) {
    int e = eidx[n * 2 + k];
    e = min(max(e, 0), E - 1);
    float w = fw[n * 2 + k];
    const float* Wr = Wea + ((long)e * A + c) * A;
    float t = 0.f;
#pragma unroll 8
    for (int a = 0; a < 128; a++) t += Wr[a] * h0s[a];
    float s = t, q = t * t;
#pragma unroll
    for (int off = 32; off; off >>= 1) { s += __shfl_xor(s, off); q += __shfl_xor(q, off); }
    if ((c & 63) == 0) { red[(c >> 6) * 2] = s; red[(c >> 6) * 2 + 1] = q; }
    __syncthreads();
    float Sx = red[0] + red[2], Qx = red[1] + red[3];
    float mean = Sx * (1.f / 128.f);
    float var = Qx * (1.f / 128.f) - mean * mean;
    float r = rsqrtf(var + 1e-5f);
    out += w * ((t - mean) * r * ln_eg[e * A + c] + ln_eb[e * A + c]);
    __syncthreads();
  }
  hw[(long)n * A + c] = out;
}

__global__ void zero_loss(float* loss) {
  if (threadIdx.x < 16) loss[threadIdx.x] = 0.f;
}

__global__ void finalize_loss(const float* __restrict__ loss, float* __restrict__ out) {
  if (threadIdx.x != 0) return;
  float tl = 0.f;
  for (int e = 0; e < 8; e++) tl += loss[e];
  float target = tl / 8.f;
  float mse = 0.f;
  for (int e = 0; e < 8; e++) { float d = loss[e] - target; mse += d * d; }
  mse *= (1.f / 8.f);
  float r = 0.001f * (mse + loss[8] / (float)(N * 2) + loss[9] / (float)(N * 4));
  out[0] = r;
}

// ---------------------------------------------------------------------------
extern "C" void kernel_launch(void* const* d_in, const int* in_sizes, int n_in,
                              void* d_out, int out_size, void* d_ws, size_t ws_size,
                              hipStream_t stream) {
  const float* x = (const float*)d_in[0];
  const float* Wu = (const float*)d_in[1];
  const float* Wg = (const float*)d_in[2];
  const float* Wd = (const float*)d_in[3];
  const float* Wpre = (const float*)d_in[4];
  const float* Wpost = (const float*)d_in[5];
  const float* ln_g = (const float*)d_in[6];
  const float* ln_b = (const float*)d_in[7];
  const float* Wap = (const float*)d_in[8];
  const float* Wea = (const float*)d_in[9];
  const float* ln_eg = (const float*)d_in[10];
  const float* ln_eb = (const float*)d_in[11];
  const float* Wep = (const float*)d_in[12];
  const float* Wop = (const float*)d_in[13];
  const float* Wgr = (const float*)d_in[14];
  const float* Wer = (const float*)d_in[15];
  float* out = (float*)d_out;   // <-- ROUND 6: output is FLOAT32

  char* ws = (char*)d_ws;
  size_t off = 0;
  auto alloc = [&](size_t bytes) { char* p = ws + off; off += (bytes + 255) & ~size_t(255); return p; };
  float* loss = (float*)alloc(64);
  float* wsum = (float*)alloc((size_t)N * 4);
  float* fwb = (float*)alloc((size_t)N * 2 * 4);
  int* eidx = (int*)alloc((size_t)N * 2 * 4);
  float* Mf = (float*)alloc((size_t)D * A * 4);       // 0.5 MB
  float* h0f = (float*)alloc((size_t)N * A * 4);      // 4 MB
  float* aif = (float*)alloc((size_t)N * A * 4);      // 4 MB
  float* aopref = (float*)alloc((size_t)N * A * 4);   // 4 MB
  float* aof = (float*)alloc((size_t)N * A * 4);      // 4 MB
  float* adpref = (float*)alloc((size_t)N * A * 4);   // 4 MB
  float* hwf = (float*)alloc((size_t)N * A * 4);      // 4 MB
  bf16_t* awb = (bf16_t*)alloc((size_t)S * S * 2);    // 8 MB (one batch)
  bf16_t* hidden = (bf16_t*)alloc((size_t)N * H * 2); // 32 MB
  (void)ws_size; (void)in_sizes; (void)n_in; (void)out_size;

  const dim3 blk(256);

  zero_loss<<<dim3(1), dim3(64), 0, stream>>>(loss);
  router_kernel<<<dim3(N / 4), blk, 0, stream>>>(x, Wgr, Wer, eidx, fwb, wsum, loss);
  // hidden = silu(x@Wg^T) * (x@Wu^T)   [N,H] K=D
  gateup16<<<dim3(H / 16, N / 16), blk, 0, stream>>>(x, Wg, Wu, hidden, N, H, D);
  // h0 = x@Wpre^T   [N,A] K=D  (f32)
  gemm16<0, 0, 0, 0><<<dim3(A / 16, N / 16), blk, 0, stream>>>(x, Wpre, h0f, N, A, D, nullptr);
  ln_rows_f32<<<dim3(N / 4), blk, 0, stream>>>(h0f, ln_g, ln_b, aif);
  // ao_pre = hidden@Wpost^T   [N,A] K=H  (A bf16)
  gemm16<1, 0, 0, 0><<<dim3(A / 16, N / 16), blk, 0, stream>>>(hidden, Wpost, aopref, N, A, H, nullptr);
  ln_rows_f32<<<dim3(N / 4), blk, 0, stream>>>(aopref, ln_g, ln_b, aof);
  // per batch: aw_b = silu(clip(ai_b@ao_b^T)); adpre_b = aw_b @ ai_b (NN)
  for (int b = 0; b < Bb; b++) {
    const float* ai_b = aif + (size_t)b * S * A;
    const float* ao_b = aof + (size_t)b * S * A;
    float* adpre_b = adpref + (size_t)b * S * A;
    gemm16<0, 0, 0, 2><<<dim3(S / 16, S / 16), blk, 0, stream>>>(ai_b, ao_b, awb, S, S, A, nullptr);
    gemm16<1, 0, 1, 0><<<dim3(A / 16, S / 16), blk, 0, stream>>>(awb, ai_b, adpre_b, S, A, S, nullptr);
  }
  // hidden += 0.1 * adpre @ Wap^T   [N,H] K=A  (bf16 RMW)
  gemm16<0, 0, 0, 3><<<dim3(H / 16, N / 16), blk, 0, stream>>>(adpref, Wap, hidden, N, H, A, nullptr);
  // out = shared = hidden @ Wd^T   [N,D] K=H  (f32 -> d_out)
  gemm16<1, 0, 0, 0><<<dim3(D / 16, N / 16), blk, 0, stream>>>(hidden, Wd, out, N, D, H, nullptr);
  // M = Wop @ Wep   [D,A] K=H  (NN, f32)
  gemm16<0, 0, 1, 0><<<dim3(A / 16, D / 16), blk, 0, stream>>>(Wop, Wep, Mf, D, A, H, nullptr);
  // hw = sum_k fw_k * LN_e(Wea[e_k] @ h0)
  expert_adapt_f32<<<dim3(N), dim3(128), 0, stream>>>(h0f, Wea, ln_eg, ln_eb, eidx, fwb, hwf);
  // out = out*wsum[row] + 0.1 * hw @ M^T   [N,D] K=A  (f32 in-place RMW)
  gemm16<0, 0, 0, 5><<<dim3(D / 16, N / 16), blk, 0, stream>>>(hwf, Mf, out, N, D, A, wsum);
  finalize_loss<<<dim3(1), dim3(64), 0, stream>>>(loss, out + (size_t)N * D);
}

// Round 7
// 1540.773 us; speedup vs baseline: 4.7656x; 4.7656x over previous
//
#include <hip/hip_runtime.h>
#include <math.h>

// ---------------------------------------------------------------------------
// MoE layer, round 7: MFMA pipeline. Inputs f32, output f32 (proven R6).
// Main path (gateup, down-proj): split-precision bf16 MFMA (hi/lo, 3 terms)
//   -> ~f32 accuracy. hidden kept f32 in ws.
// Damped paths (adapt, experts, router aux): plain bf16 MFMA / f32 VALU.
// B=4, S=2048, D=1024, H=2048, A=128, E=8, N=8192.
// ---------------------------------------------------------------------------

typedef __bf16 bf16_t;
typedef __attribute__((ext_vector_type(8))) __bf16 bf16x8;
typedef __attribute__((ext_vector_type(4))) float f32x4;

__device__ __forceinline__ float b2f(bf16_t v) { return (float)v; }
__device__ __forceinline__ bf16_t f2b(float v) { return (bf16_t)v; }
__device__ __forceinline__ float siluf(float v) { return v / (1.f + expf(-v)); }

static constexpr int Bb = 4, S = 2048, D = 1024, H = 2048, A = 128, E = 8;
static constexpr int N = Bb * S;

// 8 consecutive f32 -> bf16 (plain round)
__device__ __forceinline__ bf16x8 ld8f(const float* p) {
  float4 a = *reinterpret_cast<const float4*>(p);
  float4 b = *reinterpret_cast<const float4*>(p + 4);
  bf16x8 r;
  r[0] = f2b(a.x); r[1] = f2b(a.y); r[2] = f2b(a.z); r[3] = f2b(a.w);
  r[4] = f2b(b.x); r[5] = f2b(b.y); r[6] = f2b(b.z); r[7] = f2b(b.w);
  return r;
}
// 8 consecutive f32 -> hi/lo bf16 split
__device__ __forceinline__ void split8(const float* p, bf16x8& h, bf16x8& l) {
  float4 a = *reinterpret_cast<const float4*>(p);
  float4 b = *reinterpret_cast<const float4*>(p + 4);
  float v[8] = {a.x, a.y, a.z, a.w, b.x, b.y, b.z, b.w};
#pragma unroll
  for (int j = 0; j < 8; j++) {
    bf16_t hh = f2b(v[j]);
    h[j] = hh;
    l[j] = f2b(v[j] - b2f(hh));
  }
}
// mixed loader for plain-bf16 GEMM staging
__device__ __forceinline__ bf16x8 ld8(const void* p, long i, int isf) {
  if (isf) return ld8f(reinterpret_cast<const float*>(p) + i);
  return *reinterpret_cast<const bf16x8*>(reinterpret_cast<const bf16_t*>(p) + i);
}

// ---------------------------------------------------------------------------
// Plain-bf16 NT GEMM (verified layout, R4==R5 bit-identical).
// MODE: 0 bf16 store; 1 silu(clip(v,-5,5)) bf16; 2 f32 RMW C += 0.1*v;
//       3 f32 RMW C = C*aux[row] + 0.1*v
// ---------------------------------------------------------------------------
template <int WM, int WN, int MODE>
__global__ __launch_bounds__(256) void gemm_nt_b(
    const void* __restrict__ Ag, const void* __restrict__ Bg,
    void* __restrict__ Cv, int M, int Nn, int K,
    const float* __restrict__ aux, int aF, int bF) {
  constexpr int BM = 2 * WM, BN = 2 * WN, AM = WM / 16, AN = WN / 16;
  constexpr int LDT = 40;
  __shared__ alignas(16) bf16_t As[BM * LDT];
  __shared__ alignas(16) bf16_t Bs[BN * LDT];

  const int tid = threadIdx.x;
  const int wave = tid >> 6, lane = tid & 63;
  const int wr = wave >> 1, wc = wave & 1;
  const int quad = lane >> 4, l16 = lane & 15;
  const int rowA0 = blockIdx.y * BM, rowB0 = blockIdx.x * BN;

  f32x4 acc[AM][AN] = {};

  for (int k0 = 0; k0 < K; k0 += 32) {
    for (int c = tid; c < BM * 4; c += 256) {
      int r = c >> 2, kc = c & 3;
      *reinterpret_cast<bf16x8*>(&As[r * LDT + kc * 8]) =
          ld8(Ag, (long)(rowA0 + r) * K + k0 + kc * 8, aF);
    }
    for (int c = tid; c < BN * 4; c += 256) {
      int r = c >> 2, kc = c & 3;
      *reinterpret_cast<bf16x8*>(&Bs[r * LDT + kc * 8]) =
          ld8(Bg, (long)(rowB0 + r) * K + k0 + kc * 8, bF);
    }
    __syncthreads();
    bf16x8 af[AM], bfv[AN];
#pragma unroll
    for (int i = 0; i < AM; i++)
      af[i] = *reinterpret_cast<bf16x8*>(&As[(wr * WM + i * 16 + l16) * LDT + quad * 8]);
#pragma unroll
    for (int j = 0; j < AN; j++)
      bfv[j] = *reinterpret_cast<bf16x8*>(&Bs[(wc * WN + j * 16 + l16) * LDT + quad * 8]);
#pragma unroll
    for (int i = 0; i < AM; i++)
#pragma unroll
      for (int j = 0; j < AN; j++)
        acc[i][j] = __builtin_amdgcn_mfma_f32_16x16x32_bf16(af[i], bfv[j], acc[i][j], 0, 0, 0);
    __syncthreads();
  }

  // C/D: col = lane&15, row = quad*4 + reg
#pragma unroll
  for (int i = 0; i < AM; i++)
#pragma unroll
    for (int j = 0; j < AN; j++)
#pragma unroll
      for (int r = 0; r < 4; r++) {
        int row = rowA0 + wr * WM + i * 16 + quad * 4 + r;
        int col = rowB0 + wc * WN + j * 16 + l16;
        long o = (long)row * Nn + col;
        float v = acc[i][j][r];
        if constexpr (MODE == 0) {
          reinterpret_cast<bf16_t*>(Cv)[o] = f2b(v);
        } else if constexpr (MODE == 1) {
          v = fminf(fmaxf(v, -5.f), 5.f);
          reinterpret_cast<bf16_t*>(Cv)[o] = f2b(siluf(v));
        } else if constexpr (MODE == 2) {
          float* C = reinterpret_cast<float*>(Cv);
          C[o] = C[o] + 0.1f * v;
        } else {
          float* C = reinterpret_cast<float*>(Cv);
          C[o] = C[o] * aux[row] + 0.1f * v;
        }
      }
}

// ---------------------------------------------------------------------------
// Split-precision (hi/lo) down-proj GEMM: C_f32 = A_f32 @ B_f32^T.
// 128x128 tile, 3 MFMAs per (i,j) per k-step.
// ---------------------------------------------------------------------------
__global__ __launch_bounds__(256) void gemm_dn_hl(
    const float* __restrict__ Ag, const float* __restrict__ Bg,
    float* __restrict__ Cg, int M, int Nn, int K) {
  constexpr int BM = 128, BN = 128, LDT = 40;
  __shared__ alignas(16) bf16_t Ah[BM * LDT];
  __shared__ alignas(16) bf16_t Al[BM * LDT];
  __shared__ alignas(16) bf16_t Bh[BN * LDT];
  __shared__ alignas(16) bf16_t Bl[BN * LDT];

  const int tid = threadIdx.x;
  const int wave = tid >> 6, lane = tid & 63;
  const int wr = wave >> 1, wc = wave & 1;
  const int quad = lane >> 4, l16 = lane & 15;
  const int rowA0 = blockIdx.y * BM, rowB0 = blockIdx.x * BN;

  f32x4 acc[4][4] = {};

  for (int k0 = 0; k0 < K; k0 += 32) {
    for (int c = tid; c < BM * 4; c += 256) {
      int r = c >> 2, kc = c & 3;
      bf16x8 h, l;
      split8(&Ag[(long)(rowA0 + r) * K + k0 + kc * 8], h, l);
      *reinterpret_cast<bf16x8*>(&Ah[r * LDT + kc * 8]) = h;
      *reinterpret_cast<bf16x8*>(&Al[r * LDT + kc * 8]) = l;
    }
    for (int c = tid; c < BN * 4; c += 256) {
      int r = c >> 2, kc = c & 3;
      bf16x8 h, l;
      split8(&Bg[(long)(rowB0 + r) * K + k0 + kc * 8], h, l);
      *reinterpret_cast<bf16x8*>(&Bh[r * LDT + kc * 8]) = h;
      *reinterpret_cast<bf16x8*>(&Bl[r * LDT + kc * 8]) = l;
    }
    __syncthreads();
    bf16x8 afh[4], afl[4], bfh[4], bfl[4];
#pragma unroll
    for (int i = 0; i < 4; i++) {
      int ro = (wr * 64 + i * 16 + l16) * LDT + quad * 8;
      afh[i] = *reinterpret_cast<bf16x8*>(&Ah[ro]);
      afl[i] = *reinterpret_cast<bf16x8*>(&Al[ro]);
    }
#pragma unroll
    for (int j = 0; j < 4; j++) {
      int ro = (wc * 64 + j * 16 + l16) * LDT + quad * 8;
      bfh[j] = *reinterpret_cast<bf16x8*>(&Bh[ro]);
      bfl[j] = *reinterpret_cast<bf16x8*>(&Bl[ro]);
    }
#pragma unroll
    for (int i = 0; i < 4; i++)
#pragma unroll
      for (int j = 0; j < 4; j++) {
        acc[i][j] = __builtin_amdgcn_mfma_f32_16x16x32_bf16(afh[i], bfh[j], acc[i][j], 0, 0, 0);
        acc[i][j] = __builtin_amdgcn_mfma_f32_16x16x32_bf16(afh[i], bfl[j], acc[i][j], 0, 0, 0);
        acc[i][j] = __builtin_amdgcn_mfma_f32_16x16x32_bf16(afl[i], bfh[j], acc[i][j], 0, 0, 0);
      }
    __syncthreads();
  }

#pragma unroll
  for (int i = 0; i < 4; i++)
#pragma unroll
    for (int j = 0; j < 4; j++)
#pragma unroll
      for (int r = 0; r < 4; r++) {
        int row = rowA0 + wr * 64 + i * 16 + quad * 4 + r;
        int col = rowB0 + wc * 64 + j * 16 + l16;
        Cg[(long)row * Nn + col] = acc[i][j][r];
      }
}

// ---------------------------------------------------------------------------
// Split-precision fused gate/up: hidden_f32 = silu(x@Wg^T)*(x@Wu^T).
// 128x64 tile; 6 MFMAs per (i,j) per k-step.
// ---------------------------------------------------------------------------
__global__ __launch_bounds__(256) void gemm_gu_hl(
    const float* __restrict__ x, const float* __restrict__ Wg,
    const float* __restrict__ Wu, float* __restrict__ Cg, int M, int Nn, int K) {
  constexpr int BM = 128, BN = 64, LDT = 40;
  __shared__ alignas(16) bf16_t Ah[BM * LDT];
  __shared__ alignas(16) bf16_t Al[BM * LDT];
  __shared__ alignas(16) bf16_t B1h[BN * LDT];
  __shared__ alignas(16) bf16_t B1l[BN * LDT];
  __shared__ alignas(16) bf16_t B2h[BN * LDT];
  __shared__ alignas(16) bf16_t B2l[BN * LDT];

  const int tid = threadIdx.x;
  const int wave = tid >> 6, lane = tid & 63;
  const int wr = wave >> 1, wc = wave & 1;
  const int quad = lane >> 4, l16 = lane & 15;
  const int rowA0 = blockIdx.y * BM, rowB0 = blockIdx.x * BN;

  f32x4 ag[4][2] = {}, au[4][2] = {};

  for (int k0 = 0; k0 < K; k0 += 32) {
    for (int c = tid; c < BM * 4; c += 256) {
      int r = c >> 2, kc = c & 3;
      bf16x8 h, l;
      split8(&x[(long)(rowA0 + r) * K + k0 + kc * 8], h, l);
      *reinterpret_cast<bf16x8*>(&Ah[r * LDT + kc * 8]) = h;
      *reinterpret_cast<bf16x8*>(&Al[r * LDT + kc * 8]) = l;
    }
    for (int c = tid; c < BN * 4; c += 256) {
      int r = c >> 2, kc = c & 3;
      long idx = (long)(rowB0 + r) * K + k0 + kc * 8;
      bf16x8 h, l;
      split8(&Wg[idx], h, l);
      *reinterpret_cast<bf16x8*>(&B1h[r * LDT + kc * 8]) = h;
      *reinterpret_cast<bf16x8*>(&B1l[r * LDT + kc * 8]) = l;
      split8(&Wu[idx], h, l);
      *reinterpret_cast<bf16x8*>(&B2h[r * LDT + kc * 8]) = h;
      *reinterpret_cast<bf16x8*>(&B2l[r * LDT + kc * 8]) = l;
    }
    __syncthreads();
    bf16x8 afh[4], afl[4], b1h[2], b1l[2], b2h[2], b2l[2];
#pragma unroll
    for (int i = 0; i < 4; i++) {
      int ro = (wr * 64 + i * 16 + l16) * LDT + quad * 8;
      afh[i] = *reinterpret_cast<bf16x8*>(&Ah[ro]);
      afl[i] = *reinterpret_cast<bf16x8*>(&Al[ro]);
    }
#pragma unroll
    for (int j = 0; j < 2; j++) {
      int ro = (wc * 32 + j * 16 + l16) * LDT + quad * 8;
      b1h[j] = *reinterpret_cast<bf16x8*>(&B1h[ro]);
      b1l[j] = *reinterpret_cast<bf16x8*>(&B1l[ro]);
      b2h[j] = *reinterpret_cast<bf16x8*>(&B2h[ro]);
      b2l[j] = *reinterpret_cast<bf16x8*>(&B2l[ro]);
    }
#pragma unroll
    for (int i = 0; i < 4; i++)
#pragma unroll
      for (int j = 0; j < 2; j++) {
        ag[i][j] = __builtin_amdgcn_mfma_f32_16x16x32_bf16(afh[i], b1h[j], ag[i][j], 0, 0, 0);
        ag[i][j] = __builtin_amdgcn_mfma_f32_16x16x32_bf16(afh[i], b1l[j], ag[i][j], 0, 0, 0);
        ag[i][j] = __builtin_amdgcn_mfma_f32_16x16x32_bf16(afl[i], b1h[j], ag[i][j], 0, 0, 0);
        au[i][j] = __builtin_amdgcn_mfma_f32_16x16x32_bf16(afh[i], b2h[j], au[i][j], 0, 0, 0);
        au[i][j] = __builtin_amdgcn_mfma_f32_16x16x32_bf16(afh[i], b2l[j], au[i][j], 0, 0, 0);
        au[i][j] = __builtin_amdgcn_mfma_f32_16x16x32_bf16(afl[i], b2h[j], au[i][j], 0, 0, 0);
      }
    __syncthreads();
  }

#pragma unroll
  for (int i = 0; i < 4; i++)
#pragma unroll
    for (int j = 0; j < 2; j++)
#pragma unroll
      for (int r = 0; r < 4; r++) {
        int row = rowA0 + wr * 64 + i * 16 + quad * 4 + r;
        int col = rowB0 + wc * 32 + j * 16 + l16;
        Cg[(long)row * Nn + col] = siluf(ag[i][j][r]) * au[i][j][r];
      }
}

// ---------------------------------------------------------------------------
// Router (proven R6).
// ---------------------------------------------------------------------------
__global__ __launch_bounds__(256) void router_kernel(
    const float* __restrict__ x, const float* __restrict__ Wgr,
    const float* __restrict__ Wer, int* __restrict__ eidx,
    float* __restrict__ fw, float* __restrict__ wsum, float* __restrict__ loss) {
  const int token = blockIdx.x * 4 + (threadIdx.x >> 6);
  const int lane = threadIdx.x & 63;
  const float* xp = x + (long)token * D;
  float xr[16];
#pragma unroll
  for (int i = 0; i < 16; i++) xr[i] = xp[lane + i * 64];
  float dots[6];
#pragma unroll
  for (int w = 0; w < 6; w++) {
    const float* wp = (w < 2) ? (Wgr + (long)w * D) : (Wer + (long)(w - 2) * D);
    float s = 0.f;
#pragma unroll
    for (int i = 0; i < 16; i++) s += xr[i] * wp[lane + i * 64];
#pragma unroll
    for (int off = 32; off; off >>= 1) s += __shfl_xor(s, off);
    dots[w] = s;
  }
  if (lane == 0) {
    float gl0 = dots[0], gl1 = dots[1];
    float mg = fmaxf(gl0, gl1);
    float e0 = expf(gl0 - mg), e1 = expf(gl1 - mg);
    float inv = 1.f / (e0 + e1);
    float gp0 = e0 * inv, gp1 = e1 * inv;
    int gi = (gp1 > gp0) ? 1 : 0;
    float gw = gi ? gp1 : gp0;
    float el[4] = {dots[2], dots[3], dots[4], dots[5]};
    float me = fmaxf(fmaxf(el[0], el[1]), fmaxf(el[2], el[3]));
    float ep[4], es = 0.f;
#pragma unroll
    for (int j = 0; j < 4; j++) { ep[j] = expf(el[j] - me); es += ep[j]; }
    float inve = 1.f / es;
#pragma unroll
    for (int j = 0; j < 4; j++) ep[j] *= inve;
    int i1 = 0;
    for (int j = 1; j < 4; j++) if (ep[j] > ep[i1]) i1 = j;
    int i2 = (i1 == 0) ? 1 : 0;
    for (int j = 0; j < 4; j++) if (j != i1 && j != i2 && ep[j] > ep[i2]) i2 = j;
    float l1 = ep[i1], l2 = ep[i2];
    float ils = 1.f / (l1 + l2 + 1e-7f);
    float f1 = gw * l1 * ils, f2 = gw * l2 * ils;
    eidx[token * 2] = gi * 4 + i1;
    eidx[token * 2 + 1] = gi * 4 + i2;
    fw[token * 2] = f1;
    fw[token * 2 + 1] = f2;
    wsum[token] = f1 + f2;
    atomicAdd(&loss[gi * 4 + i1], f1);
    atomicAdd(&loss[gi * 4 + i2], f2);
    atomicAdd(&loss[8], gl0 * gl0 + gl1 * gl1);
    atomicAdd(&loss[9], el[0] * el[0] + el[1] * el[1] + el[2] * el[2] + el[3] * el[3]);
  }
}

// ---------------------------------------------------------------------------
// Row LayerNorm over A=128 (bf16 in ws, f32 g/b, bf16 out).
// ---------------------------------------------------------------------------
__global__ __launch_bounds__(256) void ln_rows(
    const bf16_t* __restrict__ in, const float* __restrict__ g,
    const float* __restrict__ b, bf16_t* __restrict__ out) {
  const int row = blockIdx.x * 4 + (threadIdx.x >> 6);
  const int lane = threadIdx.x & 63;
  const bf16_t* p = in + (long)row * A;
  float x0 = b2f(p[lane]), x1 = b2f(p[lane + 64]);
  float s = x0 + x1;
#pragma unroll
  for (int off = 32; off; off >>= 1) s += __shfl_xor(s, off);
  float mean = s * (1.f / 128.f);
  float d0 = x0 - mean, d1 = x1 - mean;
  float q = d0 * d0 + d1 * d1;
#pragma unroll
  for (int off = 32; off; off >>= 1) q += __shfl_xor(q, off);
  float r = rsqrtf(q * (1.f / 128.f) + 1e-5f);
  bf16_t* po = out + (long)row * A;
  po[lane] = f2b(d0 * r * g[lane] + b[lane]);
  po[lane + 64] = f2b(d1 * r * g[lane + 64] + b[lane + 64]);
}

// ---------------------------------------------------------------------------
// Transpose [z,R,C] -> [z,C,R], bf16 out; input f32 (isf=1) or bf16.
// ---------------------------------------------------------------------------
__global__ __launch_bounds__(256) void transpose2d(
    const void* __restrict__ in, bf16_t* __restrict__ out, int R, int C, int isf) {
  __shared__ bf16_t t[32][33];
  const long zb = blockIdx.z;
  const long ib = zb * (long)R * C;
  bf16_t* op = out + zb * (long)R * C;
  const int r0 = blockIdx.y * 32, c0 = blockIdx.x * 32;
  const int tx = threadIdx.x & 31, ty = threadIdx.x >> 5;
#pragma unroll
  for (int i = 0; i < 4; i++) {
    long idx = ib + (long)(r0 + ty + i * 8) * C + c0 + tx;
    t[ty + i * 8][tx] = isf ? f2b(reinterpret_cast<const float*>(in)[idx])
                            : reinterpret_cast<const bf16_t*>(in)[idx];
  }
  __syncthreads();
#pragma unroll
  for (int i = 0; i < 4; i++) op[(long)(c0 + ty + i * 8) * R + r0 + tx] = t[tx][ty + i * 8];
}

// ---------------------------------------------------------------------------
// Expert branch (f32 math, h0 from bf16 ws).
// ---------------------------------------------------------------------------
__global__ __launch_bounds__(128) void expert_adapt(
    const bf16_t* __restrict__ h0, const float* __restrict__ Wea,
    const float* __restrict__ ln_eg, const float* __restrict__ ln_eb,
    const int* __restrict__ eidx, const float* __restrict__ fw,
    bf16_t* __restrict__ hw) {
  const int n = blockIdx.x;
  const int c = threadIdx.x;
  __shared__ float h0s[128];
  __shared__ float red[4];
  h0s[c] = b2f(h0[(long)n * A + c]);
  __syncthreads();
  float out = 0.f;
  for (int k = 0; k < 2; k++) {
    int e = eidx[n * 2 + k];
    e = min(max(e, 0), E - 1);
    float w = fw[n * 2 + k];
    const float* Wr = Wea + ((long)e * A + c) * A;
    float t = 0.f;
#pragma unroll 8
    for (int a = 0; a < 128; a++) t += Wr[a] * h0s[a];
    float s = t, q = t * t;
#pragma unroll
    for (int off = 32; off; off >>= 1) { s += __shfl_xor(s, off); q += __shfl_xor(q, off); }
    if ((c & 63) == 0) { red[(c >> 6) * 2] = s; red[(c >> 6) * 2 + 1] = q; }
    __syncthreads();
    float Sx = red[0] + red[2], Qx = red[1] + red[3];
    float mean = Sx * (1.f / 128.f);
    float var = Qx * (1.f / 128.f) - mean * mean;
    float r = rsqrtf(var + 1e-5f);
    out += w * ((t - mean) * r * ln_eg[e * A + c] + ln_eb[e * A + c]);
    __syncthreads();
  }
  hw[(long)n * A + c] = f2b(out);
}

__global__ void zero_loss(float* loss) {
  if (threadIdx.x < 16) loss[threadIdx.x] = 0.f;
}

__global__ void finalize_loss(const float* __restrict__ loss, float* __restrict__ out) {
  if (threadIdx.x != 0) return;
  float tl = 0.f;
  for (int e = 0; e < 8; e++) tl += loss[e];
  float target = tl / 8.f;
  float mse = 0.f;
  for (int e = 0; e < 8; e++) { float d = loss[e] - target; mse += d * d; }
  mse *= (1.f / 8.f);
  float r = 0.001f * (mse + loss[8] / (float)(N * 2) + loss[9] / (float)(N * 4));
  out[0] = r;
}

// ---------------------------------------------------------------------------
extern "C" void kernel_launch(void* const* d_in, const int* in_sizes, int n_in,
                              void* d_out, int out_size, void* d_ws, size_t ws_size,
                              hipStream_t stream) {
  const float* x = (const float*)d_in[0];
  const float* Wu = (const float*)d_in[1];
  const float* Wg = (const float*)d_in[2];
  const float* Wd = (const float*)d_in[3];
  const float* Wpre = (const float*)d_in[4];
  const float* Wpost = (const float*)d_in[5];
  const float* ln_g = (const float*)d_in[6];
  const float* ln_b = (const float*)d_in[7];
  const float* Wap = (const float*)d_in[8];
  const float* Wea = (const float*)d_in[9];
  const float* ln_eg = (const float*)d_in[10];
  const float* ln_eb = (const float*)d_in[11];
  const float* Wep = (const float*)d_in[12];
  const float* Wop = (const float*)d_in[13];
  const float* Wgr = (const float*)d_in[14];
  const float* Wer = (const float*)d_in[15];
  float* out = (float*)d_out;

  // Workspace ~83 MB (ws >= ~91 MB proven by R3/R4 equivalence).
  char* ws = (char*)d_ws;
  size_t off = 0;
  auto alloc = [&](size_t bytes) { char* p = ws + off; off += (bytes + 255) & ~size_t(255); return p; };
  float* loss = (float*)alloc(64);
  float* wsum = (float*)alloc((size_t)N * 4);
  float* fwb = (float*)alloc((size_t)N * 2 * 4);
  int* eidx = (int*)alloc((size_t)N * 2 * 4);
  bf16_t* Mb = (bf16_t*)alloc((size_t)D * A * 2);      // 256 KB
  bf16_t* WepT = (bf16_t*)alloc((size_t)H * A * 2);    // 512 KB
  bf16_t* hwb = (bf16_t*)alloc((size_t)N * A * 2);     // 2 MB
  bf16_t* h0b = (bf16_t*)alloc((size_t)N * A * 2);     // 2 MB
  bf16_t* aib = (bf16_t*)alloc((size_t)N * A * 2);     // 2 MB
  bf16_t* scrA = (bf16_t*)alloc((size_t)N * A * 2);    // 2 MB  (aopre -> aiT)
  bf16_t* scrB = (bf16_t*)alloc((size_t)N * A * 2);    // 2 MB  (aob -> adpre)
  bf16_t* awb = (bf16_t*)alloc((size_t)S * S * 2);     // 8 MB  (one batch)
  float* hiddenF = (float*)alloc((size_t)N * H * 4);   // 64 MB
  bf16_t* aopre = scrA;
  bf16_t* aiT = scrA;
  bf16_t* aob = scrB;
  bf16_t* adpre = scrB;
  (void)ws_size; (void)in_sizes; (void)n_in; (void)out_size;

  const dim3 blk(256);

  zero_loss<<<dim3(1), dim3(64), 0, stream>>>(loss);
  router_kernel<<<dim3(N / 4), blk, 0, stream>>>(x, Wgr, Wer, eidx, fwb, wsum, loss);
  // hidden = silu(x@Wg^T)*(x@Wu^T)  f32, split-precision  [N,H] K=D
  gemm_gu_hl<<<dim3(H / 64, N / 128), blk, 0, stream>>>(x, Wg, Wu, hiddenF, N, H, D);
  // h0 = x@Wpre^T  [N,A] K=D (plain bf16)
  gemm_nt_b<32, 32, 0><<<dim3(A / 64, N / 64), blk, 0, stream>>>(
      x, Wpre, h0b, N, A, D, nullptr, 1, 1);
  ln_rows<<<dim3(N / 4), blk, 0, stream>>>(h0b, ln_g, ln_b, aib);
  // ao_pre = hidden@Wpost^T  [N,A] K=H (plain bf16; A from f32 hidden)
  gemm_nt_b<32, 32, 0><<<dim3(A / 64, N / 64), blk, 0, stream>>>(
      hiddenF, Wpost, aopre, N, A, H, nullptr, 1, 1);
  ln_rows<<<dim3(N / 4), blk, 0, stream>>>(aopre, ln_g, ln_b, aob);
  // aiT = ai^T per batch
  transpose2d<<<dim3(A / 32, S / 32, Bb), blk, 0, stream>>>(aib, aiT, S, A, 0);
  // per batch: aw_b = silu(clip(ai_b@ao_b^T)); adpre_b = aw_b@aiT_b^T
  for (int b = 0; b < Bb; b++) {
    const bf16_t* ai_b = aib + (size_t)b * S * A;
    const bf16_t* ao_b = aob + (size_t)b * S * A;
    const bf16_t* aiT_b = aiT + (size_t)b * A * S;
    bf16_t* adpre_b = adpre + (size_t)b * S * A;
    gemm_nt_b<64, 64, 1><<<dim3(S / 128, S / 128), blk, 0, stream>>>(
        ai_b, ao_b, awb, S, S, A, nullptr, 0, 0);
    gemm_nt_b<32, 32, 0><<<dim3(A / 64, S / 64), blk, 0, stream>>>(
        awb, aiT_b, adpre_b, S, A, S, nullptr, 0, 0);
  }
  // hidden += 0.1 * adpre@Wap^T  [N,H] K=A (f32 RMW)
  gemm_nt_b<64, 64, 2><<<dim3(H / 128, N / 128), blk, 0, stream>>>(
      adpre, Wap, hiddenF, N, H, A, nullptr, 0, 1);
  // out = shared = hidden@Wd^T  f32, split-precision  [N,D] K=H
  gemm_dn_hl<<<dim3(D / 128, N / 128), blk, 0, stream>>>(hiddenF, Wd, out, N, D, H);
  // WepT = Wep^T (f32 -> bf16)
  transpose2d<<<dim3(A / 32, H / 32, 1), blk, 0, stream>>>(Wep, WepT, H, A, 1);
  // M = Wop@Wep  [D,A] K=H (plain bf16)
  gemm_nt_b<32, 32, 0><<<dim3(A / 64, D / 64), blk, 0, stream>>>(
      Wop, WepT, Mb, D, A, H, nullptr, 1, 0);
  // hw = sum_k fw_k * LN_e(Wea[e_k]@h0)
  expert_adapt<<<dim3(N), dim3(128), 0, stream>>>(h0b, Wea, ln_eg, ln_eb, eidx, fwb, hwb);
  // out = out*wsum[row] + 0.1*hw@M^T  [N,D] K=A (f32 in-place RMW)
  gemm_nt_b<64, 64, 3><<<dim3(D / 128, N / 128), blk, 0, stream>>>(
      hwb, Mb, out, N, D, A, wsum, 0, 0);
  finalize_loss<<<dim3(1), dim3(64), 0, stream>>>(loss, out + (size_t)N * D);
}